// Round 1
// baseline (254.899 us; speedup 1.0000x reference)
//
#include <hip/hip_runtime.h>
#include <hip/hip_bf16.h>

// ScoreNormCorrectedMetric: out[b] = ||xd_b||^2 - (s_b . xd_b)^2 / (1 + ||s_b||^2),
// s = x @ W^T. Strategy: bf16 MFMA GEMM (m97 structure) with fused reduction
// epilogue; xx computed in fp32 in the same epilogue. Never materialize s.

#define MTOT 16384
#define DTOT 2048   // N == K == D

#define BM 128
#define BN 128
#define BK 32

typedef unsigned short u16;
typedef __attribute__((ext_vector_type(4))) float f32x4;
typedef __attribute__((ext_vector_type(8))) short bf16x8;
typedef __attribute__((ext_vector_type(8))) unsigned short u16x8;

__device__ __forceinline__ u16 f2bf(float f) {
    union { float f; unsigned int u; } v; v.f = f;
    unsigned int u = v.u;
    u += 0x7fffu + ((u >> 16) & 1u);   // round-to-nearest-even (inputs are finite)
    return (u16)(u >> 16);
}

__device__ __forceinline__ void gload_lds16(const void* gptr, void* ldsptr) {
    __builtin_amdgcn_global_load_lds(
        (const __attribute__((address_space(1))) unsigned int*)gptr,
        (__attribute__((address_space(3))) unsigned int*)ldsptr,
        16, 0, 0);
}

// ---------------- cast f32 -> bf16, 8 elems/thread, grid-stride ----------------
__global__ void cast_kernel(const float* __restrict__ src, u16* __restrict__ dst, int n8) {
    int stride = gridDim.x * blockDim.x;
    for (int i = blockIdx.x * blockDim.x + threadIdx.x; i < n8; i += stride) {
        f32x4 a = ((const f32x4*)src)[2 * (size_t)i];
        f32x4 b = ((const f32x4*)src)[2 * (size_t)i + 1];
        u16x8 r;
        r[0] = f2bf(a[0]); r[1] = f2bf(a[1]); r[2] = f2bf(a[2]); r[3] = f2bf(a[3]);
        r[4] = f2bf(b[0]); r[5] = f2bf(b[1]); r[6] = f2bf(b[2]); r[7] = f2bf(b[3]);
        ((u16x8*)dst)[i] = r;
    }
}

// ---------------- fused GEMM + row reductions ----------------
// grid = (MTOT/BM) * (DTOT/BN) = 128*16 = 2048 blocks, 256 threads (4 waves, 2x2).
// Each wave computes a 64x64 sub-tile as 4x4 fragments of 16x16x32 bf16 MFMA.
template <bool PRECAST>
__global__ __launch_bounds__(256)
void gemm_fused(const u16* __restrict__ xbf, const u16* __restrict__ wbf,
                const float* __restrict__ xf, const float* __restrict__ wf,
                const float* __restrict__ xdot,
                float* __restrict__ ns_acc, float* __restrict__ sx_acc,
                float* __restrict__ xx_acc) {
    __shared__ u16 As[BM * BK];   // [row][k], k contiguous
    __shared__ u16 Bs[BN * BK];   // [e]  [k], k contiguous (W is B^T layout)

    const int tid  = threadIdx.x;
    const int lane = tid & 63;
    const int wid  = tid >> 6;

    // XCD-chunked swizzle (2048 % 8 == 0 -> bijective)
    int bid = blockIdx.x;
    const int cpx = gridDim.x >> 3;
    bid = (bid & 7) * cpx + (bid >> 3);

    const int nbn  = DTOT / BN;             // 16
    const int brow = (bid / nbn) * BM;
    const int bcol = (bid % nbn) * BN;

    const int wr = wid >> 1, wc = wid & 1;  // 2x2 wave grid
    const int fr = lane & 15, fq = lane >> 4;

    f32x4 acc[4][4] = {};

    // staging addressing: thread t covers row (t>>2), k-span ((t&3)*8), 16B each,
    // two chunks (rows +0 / +64). LDS dest linear in tid*16 -> wave base + lane*16.
    const int srow = tid >> 2;
    const int skof = (tid & 3) * 8;
    const size_t a_g0 = (size_t)(brow + srow) * DTOT + skof;
    const size_t b_g0 = (size_t)(bcol + srow) * DTOT + skof;
    char* as_w0 = (char*)As + wid * 1024;
    char* bs_w0 = (char*)Bs + wid * 1024;

    for (int k0 = 0; k0 < DTOT; k0 += BK) {
        if constexpr (PRECAST) {
            gload_lds16(xbf + a_g0 + k0, as_w0);
            gload_lds16(xbf + a_g0 + (size_t)64 * DTOT + k0, as_w0 + 4096);
            gload_lds16(wbf + b_g0 + k0, bs_w0);
            gload_lds16(wbf + b_g0 + (size_t)64 * DTOT + k0, bs_w0 + 4096);
        } else {
            // on-the-fly f32->bf16: thread t covers row (t>>1), 16 elems at ((t&1)*16)
            const int r2 = tid >> 1;
            const int k2 = (tid & 1) << 4;
            const float* ap = xf + (size_t)(brow + r2) * DTOT + k0 + k2;
            const float* bp = wf + (size_t)(bcol + r2) * DTOT + k0 + k2;
            f32x4 av[4], bv[4];
#pragma unroll
            for (int q = 0; q < 4; ++q) { av[q] = ((const f32x4*)ap)[q]; bv[q] = ((const f32x4*)bp)[q]; }
            u16x8 pa0, pa1, pb0, pb1;
#pragma unroll
            for (int e = 0; e < 4; ++e) {
                pa0[e] = f2bf(av[0][e]); pa0[4 + e] = f2bf(av[1][e]);
                pa1[e] = f2bf(av[2][e]); pa1[4 + e] = f2bf(av[3][e]);
                pb0[e] = f2bf(bv[0][e]); pb0[4 + e] = f2bf(bv[1][e]);
                pb1[e] = f2bf(bv[2][e]); pb1[4 + e] = f2bf(bv[3][e]);
            }
            *(u16x8*)&As[r2 * BK + k2]     = pa0;
            *(u16x8*)&As[r2 * BK + k2 + 8] = pa1;
            *(u16x8*)&Bs[r2 * BK + k2]     = pb0;
            *(u16x8*)&Bs[r2 * BK + k2 + 8] = pb1;
        }
        __syncthreads();   // drains vmcnt (global_load_lds) / lgkmcnt (ds_write)

        bf16x8 af[4], bf[4];
#pragma unroll
        for (int m = 0; m < 4; ++m)
            af[m] = *(const bf16x8*)&As[(wr * 64 + m * 16 + fr) * BK + fq * 8];
#pragma unroll
        for (int n = 0; n < 4; ++n)
            bf[n] = *(const bf16x8*)&Bs[(wc * 64 + n * 16 + fr) * BK + fq * 8];
#pragma unroll
        for (int m = 0; m < 4; ++m)
#pragma unroll
            for (int n = 0; n < 4; ++n)
                acc[m][n] = __builtin_amdgcn_mfma_f32_16x16x32_bf16(af[m], bf[n], acc[m][n], 0, 0, 0);
        __syncthreads();   // all reads done before next stage overwrites
    }

    // Epilogue: C/D layout col = lane&15, row = (lane>>4)*4 + reg (m89-verified).
    // Per (m,j): one output row; lane's 4 cols are n*16 + fr. Reduce over fr
    // (shfl_xor 1,2,4,8), then one atomicAdd per row/quantity per wave.
    // Each (b,e) pair occurs exactly once across the grid -> xd^2 sums to xx[b].
#pragma unroll
    for (int m = 0; m < 4; ++m) {
#pragma unroll
        for (int j = 0; j < 4; ++j) {
            const int row = brow + wr * 64 + m * 16 + fq * 4 + j;
            const float* xp = xdot + (size_t)row * DTOT + bcol + wc * 64 + fr;
            float pns = 0.f, psx = 0.f, pxx = 0.f;
#pragma unroll
            for (int n = 0; n < 4; ++n) {
                float s  = acc[m][n][j];
                float xv = xp[n * 16];
                pns += s * s; psx += s * xv; pxx += xv * xv;
            }
#pragma unroll
            for (int msk = 1; msk < 16; msk <<= 1) {
                pns += __shfl_xor(pns, msk);
                psx += __shfl_xor(psx, msk);
                pxx += __shfl_xor(pxx, msk);
            }
            if (fr == 0) {
                atomicAdd(&ns_acc[row], pns);
                atomicAdd(&sx_acc[row], psx);
                atomicAdd(&xx_acc[row], pxx);
            }
        }
    }
}

__global__ void finalize_k(const float* __restrict__ ns, const float* __restrict__ sx,
                           const float* __restrict__ xx, float* __restrict__ out) {
    int i = blockIdx.x * blockDim.x + threadIdx.x;
    if (i < MTOT) out[i] = xx[i] - (sx[i] * sx[i]) / (1.0f + ns[i]);
}

extern "C" void kernel_launch(void* const* d_in, const int* in_sizes, int n_in,
                              void* d_out, int out_size, void* d_ws, size_t ws_size,
                              hipStream_t stream) {
    const float* x  = (const float*)d_in[0];
    const float* xd = (const float*)d_in[1];
    const float* W  = (const float*)d_in[2];
    float* out = (float*)d_out;

    const size_t xbf_bytes = (size_t)MTOT * DTOT * 2;   // 67.1 MB
    const size_t wbf_bytes = (size_t)DTOT * DTOT * 2;   //  8.4 MB
    const size_t acc_bytes = (size_t)3 * MTOT * 4;      //  0.2 MB
    const bool precast = ws_size >= xbf_bytes + wbf_bytes + acc_bytes;

    u16* xbf = (u16*)d_ws;
    u16* wbf = (u16*)((char*)d_ws + xbf_bytes);
    float* accs = precast ? (float*)((char*)d_ws + xbf_bytes + wbf_bytes)
                          : (float*)d_ws;
    float* nsA = accs;
    float* sxA = accs + MTOT;
    float* xxA = accs + 2 * MTOT;

    hipMemsetAsync(accs, 0, acc_bytes, stream);  // re-zero every call (no re-poison between replays)

    const int grid = (MTOT / BM) * (DTOT / BN);  // 2048
    if (precast) {
        cast_kernel<<<2048, 256, 0, stream>>>(x, xbf, MTOT * DTOT / 8);
        cast_kernel<<<512, 256, 0, stream>>>(W, wbf, DTOT * DTOT / 8);
        gemm_fused<true><<<grid, 256, 0, stream>>>(xbf, wbf, nullptr, nullptr, xd, nsA, sxA, xxA);
    } else {
        gemm_fused<false><<<grid, 256, 0, stream>>>(nullptr, nullptr, x, W, xd, nsA, sxA, xxA);
    }
    finalize_k<<<MTOT / 256, 256, 0, stream>>>(nsA, sxA, xxA, out);
}

// Round 2
// 213.274 us; speedup vs baseline: 1.1952x; 1.1952x over previous
//
#include <hip/hip_runtime.h>
#include <hip/hip_bf16.h>

// out[b] = ||xd_b||^2 - (s_b . xd_b)^2 / (1 + ||s_b||^2), s = x @ W^T.
// bf16 MFMA GEMM, 256x256 tile, BK=64, 8-phase schedule (T2 swizzle + T3/T4
// counted vmcnt + T5 setprio), fused reduction epilogue. s never materialized.

#define MTOT 16384
#define DTOT 2048
#define NTILES 32   // DTOT / 64

typedef unsigned short u16;
typedef __attribute__((ext_vector_type(4))) float f32x4;
typedef __attribute__((ext_vector_type(8))) short bf16x8;
typedef __attribute__((ext_vector_type(8))) unsigned short u16x8;

__device__ __forceinline__ u16 f2bf(float f) {
    union { float f; unsigned int u; } v; v.f = f;
    unsigned int u = v.u;
    u += 0x7fffu + ((u >> 16) & 1u);   // RNE (inputs finite)
    return (u16)(u >> 16);
}

__device__ __forceinline__ void gload_lds16(const void* gptr, void* ldsptr) {
    __builtin_amdgcn_global_load_lds(
        (const __attribute__((address_space(1))) unsigned int*)gptr,
        (__attribute__((address_space(3))) unsigned int*)ldsptr,
        16, 0, 0);
}

#define BAR()    asm volatile("s_barrier" ::: "memory")
#define WAITV(n) asm volatile("s_waitcnt vmcnt(" #n ")" ::: "memory")

// ---------------- cast f32 -> bf16 ----------------
__global__ void cast_kernel(const float* __restrict__ src, u16* __restrict__ dst, int n8) {
    int stride = gridDim.x * blockDim.x;
    for (int i = blockIdx.x * blockDim.x + threadIdx.x; i < n8; i += stride) {
        f32x4 a = ((const f32x4*)src)[2 * (size_t)i];
        f32x4 b = ((const f32x4*)src)[2 * (size_t)i + 1];
        u16x8 r;
        r[0] = f2bf(a[0]); r[1] = f2bf(a[1]); r[2] = f2bf(a[2]); r[3] = f2bf(a[3]);
        r[4] = f2bf(b[0]); r[5] = f2bf(b[1]); r[6] = f2bf(b[2]); r[7] = f2bf(b[3]);
        ((u16x8*)dst)[i] = r;
    }
}

// ---------------- 8-phase 256^2 GEMM + fused reductions ----------------
// grid = 512 blocks x 512 threads (8 waves, 2M x 4N). Per wave: 128x64 output
// as acc[8][4] 16x16 fragments. LDS 128 KiB: [2 buf][A0,A1,B0,B1 half-tiles of
// 128 rows x 64 k bf16 = 16 KiB each]. Swizzle: 16B slot ^= (local_row & 7).
// Stage pipeline (verified by region-free induction, see phase comments):
//   tile t phases stage: P0: S(t+1,A1)->buf(t+1); P2: S(t+2,B0)->buf(t);
//   P3: S(t+2,B1)+S(t+2,A0)->buf(t). Boundary: vmcnt(6) + s_barrier.
//   B region of buf(t) is last read at P1, A region at P2 (each followed by a
//   post-MFMA barrier), so the t+2 stages never overwrite live data.
__global__ __launch_bounds__(512, 2)
void gemm8(const u16* __restrict__ xbf, const u16* __restrict__ wbf,
           const float* __restrict__ xdot,
           float* __restrict__ ns_acc, float* __restrict__ sx_acc,
           float* __restrict__ xx_acc) {
    __shared__ u16 lds[65536];   // 128 KiB

    const int tid  = threadIdx.x;
    const int lane = tid & 63;
    const int wid  = tid >> 6;
    const int wr = wid >> 2, wc = wid & 3;     // 2 x 4 wave grid
    const int fr = lane & 15, fq = lane >> 4;

    // XCD swizzle: each XCD owns one full 256-col W panel (1MB, L2-resident).
    const int bid  = blockIdx.x;               // 512 blocks
    const int swz  = (bid & 7) * 64 + (bid >> 3);
    const int brow = (swz & 63) * 256;
    const int bcol = (swz >> 6) * 256;

    // stage one half-tile (128 rows x 64 k bf16 = 16KiB): 2 x 16B per thread.
    // LDS dest linear (wave-uniform base + lane*16); swizzle applied by
    // permuting the GLOBAL source slot (involution: slot ^ (row&7)).
    auto stage = [&](const u16* __restrict__ src, int growbase, int kelem, int ldsbyte) {
#pragma unroll
        for (int c = 0; c < 2; ++c) {
            const int i = c * 512 + tid;
            const int row = i >> 3, slot = i & 7;
            const u16* g = src + (size_t)(growbase + row) * DTOT + kelem + ((slot ^ (row & 7)) << 3);
            gload_lds16(g, (char*)lds + ldsbyte + i * 16);
        }
    };

    // swizzled fragment read (u16-unit index): logical slot s -> physical s^(row&7)
#define FRAG(base_u16, row, s) \
    (*(const bf16x8*)&lds[(base_u16) + (row) * 64 + (((s) ^ ((row) & 7)) << 3)])

    f32x4 acc[8][4] = {};
    bf16x8 Af[2][4], Bf[2][4];

    // ---- prologue: t0 fully + t1 {B0,B1,A0}; vmcnt(6) -> t0's 8 loads landed
    stage(xbf, brow,       0,  0);              // t0.A0
    stage(xbf, brow + 128, 0,  16384);          // t0.A1
    stage(wbf, bcol,       0,  32768);          // t0.B0
    stage(wbf, bcol + 128, 0,  49152);          // t0.B1
    stage(wbf, bcol,       64, 65536 + 32768);  // t1.B0
    stage(wbf, bcol + 128, 64, 65536 + 49152);  // t1.B1
    stage(xbf, brow,       64, 65536 + 0);      // t1.A0
    WAITV(6);
    BAR();

    for (int t = 0; t < NTILES; ++t) {
        const int cur   = t & 1;
        const int abase = cur * 32768 + wr * 8192;                 // u16 units
        const int bbase = cur * 32768 + 16384 + (wc >> 1) * 8192;
        const int brB   = (wc & 1) * 64;                           // local B row base
        const int kt1   = (t + 1 < NTILES ? t + 1 : NTILES - 1) * 64;  // clamped (tail restages same bytes)
        const int kt2   = (t + 2 < NTILES ? t + 2 : NTILES - 1) * 64;
        const int bufn  = (cur ^ 1) * 65536;   // buf of tile t+1
        const int bufc  = cur * 65536;         // buf of tile t+2 (== t's buf, freed regions)

        // ---- P0: read A[m0-3] + B[n0-1]; stage S(t+1, A1)
#pragma unroll
        for (int ks = 0; ks < 2; ++ks) {
#pragma unroll
            for (int m = 0; m < 4; ++m) Af[ks][m] = FRAG(abase, m * 16 + fr, ks * 4 + fq);
#pragma unroll
            for (int n = 0; n < 2; ++n) Bf[ks][n] = FRAG(bbase, brB + n * 16 + fr, ks * 4 + fq);
        }
        stage(xbf, brow + 128, kt1, bufn + 16384);
        BAR();
        __builtin_amdgcn_s_setprio(1);
#pragma unroll
        for (int m = 0; m < 4; ++m)
#pragma unroll
            for (int n = 0; n < 2; ++n)
#pragma unroll
                for (int ks = 0; ks < 2; ++ks)
                    acc[m][n] = __builtin_amdgcn_mfma_f32_16x16x32_bf16(Af[ks][m], Bf[ks][n], acc[m][n], 0, 0, 0);
        __builtin_amdgcn_s_setprio(0);
        BAR();

        // ---- P1: read B[n2-3]; MFMA m0-3 x n2-3   (B LDS dead after this phase)
#pragma unroll
        for (int ks = 0; ks < 2; ++ks)
#pragma unroll
            for (int n = 0; n < 2; ++n) Bf[ks][2 + n] = FRAG(bbase, brB + (2 + n) * 16 + fr, ks * 4 + fq);
        BAR();
        __builtin_amdgcn_s_setprio(1);
#pragma unroll
        for (int m = 0; m < 4; ++m)
#pragma unroll
            for (int n = 0; n < 2; ++n)
#pragma unroll
                for (int ks = 0; ks < 2; ++ks)
                    acc[m][2 + n] = __builtin_amdgcn_mfma_f32_16x16x32_bf16(Af[ks][m], Bf[ks][2 + n], acc[m][2 + n], 0, 0, 0);
        __builtin_amdgcn_s_setprio(0);
        BAR();

        // ---- P2: read A[m4-7]; stage S(t+2, B0) into freed B region; MFMA m4-7 x n2-3
#pragma unroll
        for (int ks = 0; ks < 2; ++ks)
#pragma unroll
            for (int m = 0; m < 4; ++m) Af[ks][m] = FRAG(abase, 64 + m * 16 + fr, ks * 4 + fq);
        stage(wbf, bcol, kt2, bufc + 32768);
        BAR();
        __builtin_amdgcn_s_setprio(1);
#pragma unroll
        for (int m = 0; m < 4; ++m)
#pragma unroll
            for (int n = 0; n < 2; ++n)
#pragma unroll
                for (int ks = 0; ks < 2; ++ks)
                    acc[4 + m][2 + n] = __builtin_amdgcn_mfma_f32_16x16x32_bf16(Af[ks][m], Bf[ks][2 + n], acc[4 + m][2 + n], 0, 0, 0);
        __builtin_amdgcn_s_setprio(0);
        BAR();

        // ---- P3: stage S(t+2, B1) + S(t+2, A0) (A freed at P2 barrier); MFMA m4-7 x n0-1
        stage(wbf, bcol + 128, kt2, bufc + 49152);
        stage(xbf, brow,       kt2, bufc + 0);
        BAR();
        __builtin_amdgcn_s_setprio(1);
#pragma unroll
        for (int m = 0; m < 4; ++m)
#pragma unroll
            for (int n = 0; n < 2; ++n)
#pragma unroll
                for (int ks = 0; ks < 2; ++ks)
                    acc[4 + m][n] = __builtin_amdgcn_mfma_f32_16x16x32_bf16(Af[ks][m], Bf[ks][n], acc[4 + m][n], 0, 0, 0);
        __builtin_amdgcn_s_setprio(0);
        // boundary: all of tile t+1 landed except the newest 3 half-tiles (t+2's)
        WAITV(6);
        BAR();
    }

    WAITV(0);   // drain tail stages before exit
    BAR();

    // Epilogue: C/D layout col = lane&15, row = (lane>>4)*4 + reg (m89-verified).
    // Per (m,j): one output row; reduce s^2, s*xd, xd^2 over fr (shfl_xor),
    // one atomicAdd per row/quantity per wave. Each (b,e) occurs once grid-wide.
#pragma unroll
    for (int m = 0; m < 8; ++m) {
#pragma unroll
        for (int j = 0; j < 4; ++j) {
            const int row = brow + wr * 128 + m * 16 + fq * 4 + j;
            const float* xp = xdot + (size_t)row * DTOT + bcol + wc * 64 + fr;
            float pns = 0.f, psx = 0.f, pxx = 0.f;
#pragma unroll
            for (int n = 0; n < 4; ++n) {
                float s  = acc[m][n][j];
                float xv = xp[n * 16];
                pns += s * s; psx += s * xv; pxx += xv * xv;
            }
#pragma unroll
            for (int msk = 1; msk < 16; msk <<= 1) {
                pns += __shfl_xor(pns, msk);
                psx += __shfl_xor(psx, msk);
                pxx += __shfl_xor(pxx, msk);
            }
            if (fr == 0) {
                atomicAdd(&ns_acc[row], pns);
                atomicAdd(&sx_acc[row], psx);
                atomicAdd(&xx_acc[row], pxx);
            }
        }
    }
#undef FRAG
}

__global__ void finalize_k(const float* __restrict__ ns, const float* __restrict__ sx,
                           const float* __restrict__ xx, float* __restrict__ out) {
    int i = blockIdx.x * blockDim.x + threadIdx.x;
    if (i < MTOT) out[i] = xx[i] - (sx[i] * sx[i]) / (1.0f + ns[i]);
}

extern "C" void kernel_launch(void* const* d_in, const int* in_sizes, int n_in,
                              void* d_out, int out_size, void* d_ws, size_t ws_size,
                              hipStream_t stream) {
    const float* x  = (const float*)d_in[0];
    const float* xd = (const float*)d_in[1];
    const float* W  = (const float*)d_in[2];
    float* out = (float*)d_out;

    const size_t xbf_bytes = (size_t)MTOT * DTOT * 2;   // 67.1 MB
    const size_t wbf_bytes = (size_t)DTOT * DTOT * 2;   //  8.4 MB
    const size_t acc_bytes = (size_t)3 * MTOT * 4;      //  0.2 MB

    u16* xbf = (u16*)d_ws;
    u16* wbf = (u16*)((char*)d_ws + xbf_bytes);
    float* accs = (float*)((char*)d_ws + xbf_bytes + wbf_bytes);
    float* nsA = accs;
    float* sxA = accs + MTOT;
    float* xxA = accs + 2 * MTOT;
    (void)ws_size; (void)in_sizes; (void)n_in; (void)out_size;

    hipMemsetAsync(accs, 0, acc_bytes, stream);  // re-zero every call

    cast_kernel<<<2048, 256, 0, stream>>>(x, xbf, MTOT * DTOT / 8);
    cast_kernel<<<512, 256, 0, stream>>>(W, wbf, DTOT * DTOT / 8);
    gemm8<<<512, 512, 0, stream>>>(xbf, wbf, xd, nsA, sxA, xxA);
    finalize_k<<<MTOT / 256, 256, 0, stream>>>(nsA, sxA, xxA, out);
}